// Round 9
// baseline (498.336 us; speedup 1.0000x reference)
//
#include <hip/hip_runtime.h>

#define HID 128
#define HEADS 4
#define NODES 20000
#define NEDGE 320000
#define NTOT (NEDGE + NODES)
#define NODD 512

// ---------------- CSR build ----------------
__global__ void hist_kernel(const int* __restrict__ ei, int* __restrict__ cnt) {
  int e = blockIdx.x * blockDim.x + threadIdx.x;
  if (e >= NTOT) return;
  int d = (e < NEDGE) ? ei[NEDGE + e] : (e - NEDGE);
  atomicAdd(&cnt[d], 1);
}

__global__ void scan_kernel(const int* __restrict__ cnt, int* __restrict__ row_start,
                            int* __restrict__ pos) {
  __shared__ int wsum[16];
  __shared__ int s_carry;
  int t = threadIdx.x;
  int lane = t & 63, wid = t >> 6;
  if (t == 0) s_carry = 0;
  __syncthreads();
  for (int base = 0; base < NODES; base += 1024) {
    int i = base + t;
    int v = (i < NODES) ? cnt[i] : 0;
    int x = v;
    for (int off = 1; off < 64; off <<= 1) {
      int y = __shfl_up(x, off, 64);
      if (lane >= off) x += y;
    }
    if (lane == 63) wsum[wid] = x;
    __syncthreads();
    if (wid == 0) {
      int w = (lane < 16) ? wsum[lane] : 0;
      for (int off = 1; off < 16; off <<= 1) {
        int y = __shfl_up(w, off, 64);
        if (lane >= off) w += y;
      }
      if (lane < 16) wsum[lane] = w;
    }
    __syncthreads();
    int waveoff = (wid == 0) ? 0 : wsum[wid - 1];
    int incl = s_carry + waveoff + x;
    int excl = incl - v;
    if (i < NODES) { row_start[i] = excl; pos[i] = excl; }
    __syncthreads();
    if (t == 1023) s_carry = incl;
    __syncthreads();
  }
  if (t == 0) row_start[NODES] = s_carry;
}

__global__ void scatter_kernel(const int* __restrict__ ei, int* __restrict__ pos,
                               int* __restrict__ csr_src) {
  int e = blockIdx.x * blockDim.x + threadIdx.x;
  if (e >= NTOT) return;
  int s, d;
  if (e < NEDGE) { s = ei[e]; d = ei[NEDGE + e]; } else { s = e - NEDGE; d = s; }
  int p = atomicAdd(&pos[d], 1);
  csr_src[p] = s;
}

// ---------------- node encoder ----------------
__global__ void node_enc_kernel(const float* __restrict__ x, const float* __restrict__ W,
                                const float* __restrict__ b, float* __restrict__ h) {
  int idx = blockIdx.x * blockDim.x + threadIdx.x;
  if (idx >= NODES * HID) return;
  int n = idx >> 7, d = idx & 127;
  const float* xr = x + n * 5;
  float acc = b[d];
#pragma unroll
  for (int k = 0; k < 5; k++) acc = fmaf(xr[k], W[k * HID + d], acc);
  h[idx] = fmaxf(acc, 0.f);
}

// ---------------- per-layer attention coefs ----------------
__global__ void att_c_kernel(const float* __restrict__ W, const float* __restrict__ a_src,
                             const float* __restrict__ a_dst, float* __restrict__ c_src,
                             float* __restrict__ c_dst) {
  int h = blockIdx.x;        // 0..3
  int k = threadIdx.x;       // 0..127
  const float* wr = W + k * (HEADS * HID) + h * HID;
  const float* as = a_src + h * HID;
  const float* ad = a_dst + h * HID;
  float s1 = 0.f, s2 = 0.f;
  for (int d = 0; d < HID; d++) {
    float w = wr[d];
    s1 = fmaf(w, as[d], s1);
    s2 = fmaf(w, ad[d], s2);
  }
  c_src[h * HID + k] = s1;
  c_dst[h * HID + k] = s2;
}

// e_src[n,h] = h[n,:] . c_src[h,:]   (4 nodes per block, one wave each)
__global__ __launch_bounds__(256) void e_kernel(const float* __restrict__ h,
    const float* __restrict__ c_src, const float* __restrict__ c_dst,
    float* __restrict__ e_src, float* __restrict__ e_dst) {
  int lane = threadIdx.x & 63;
  int wid = threadIdx.x >> 6;
  int n = blockIdx.x * 4 + wid;
  float v0 = h[n * HID + lane];
  float v1 = h[n * HID + 64 + lane];
#pragma unroll
  for (int hh = 0; hh < HEADS; hh++) {
    float p = v0 * c_src[hh * HID + lane] + v1 * c_src[hh * HID + 64 + lane];
#pragma unroll
    for (int m = 32; m; m >>= 1) p += __shfl_xor(p, m, 64);
    if (lane == 0) e_src[n * HEADS + hh] = p;
    float q = v0 * c_dst[hh * HID + lane] + v1 * c_dst[hh * HID + 64 + lane];
#pragma unroll
    for (int m = 32; m; m >>= 1) q += __shfl_xor(q, m, 64);
    if (lane == 0) e_dst[n * HEADS + hh] = q;
  }
}

// ---------------- per-dst softmax + aggregation of raw h ----------------
// 4 nodes per block (one wave each). map!=null: node = map[idx], compact output row.
// Gather loads are float2 per lane (dims 2*lane, 2*lane+1).
__global__ __launch_bounds__(256) void agg_kernel(const float* __restrict__ h,
    const float* __restrict__ e_src, const float* __restrict__ e_dst,
    const int* __restrict__ row_start, const int* __restrict__ csr_src,
    float* __restrict__ agg, const int* __restrict__ map) {
  __shared__ float4 wsh[4][128];
  __shared__ int ssh[4][128];
  int lane = threadIdx.x & 63;
  int wid = threadIdx.x >> 6;
  int idx = blockIdx.x * 4 + wid;
  int n = map ? map[idx] : idx;
  int r0 = row_start[n], r1 = row_start[n + 1];
  int deg = r1 - r0;
  const float4* es4 = (const float4*)e_src;
  float4 ed = ((const float4*)e_dst)[n];

  int s0 = -1, s1 = -1;
  float4 v0 = {-1e30f, -1e30f, -1e30f, -1e30f};
  float4 v1 = {-1e30f, -1e30f, -1e30f, -1e30f};
  {
    int e = r0 + lane;
    if (e < r1) {
      s0 = csr_src[e];
      float4 es = es4[s0];
      float a = es.x + ed.x, b = es.y + ed.y, c = es.z + ed.z, d = es.w + ed.w;
      v0.x = a > 0.f ? a : 0.2f * a; v0.y = b > 0.f ? b : 0.2f * b;
      v0.z = c > 0.f ? c : 0.2f * c; v0.w = d > 0.f ? d : 0.2f * d;
    }
    e = r0 + 64 + lane;
    if (e < r1) {
      s1 = csr_src[e];
      float4 es = es4[s1];
      float a = es.x + ed.x, b = es.y + ed.y, c = es.z + ed.z, d = es.w + ed.w;
      v1.x = a > 0.f ? a : 0.2f * a; v1.y = b > 0.f ? b : 0.2f * b;
      v1.z = c > 0.f ? c : 0.2f * c; v1.w = d > 0.f ? d : 0.2f * d;
    }
  }
  float4 mx;
  mx.x = fmaxf(v0.x, v1.x); mx.y = fmaxf(v0.y, v1.y);
  mx.z = fmaxf(v0.z, v1.z); mx.w = fmaxf(v0.w, v1.w);
  for (int e = r0 + 128 + lane; e < r1; e += 64) {
    int s = csr_src[e];
    float4 es = es4[s];
    float a = es.x + ed.x, b = es.y + ed.y, c = es.z + ed.z, d = es.w + ed.w;
    mx.x = fmaxf(mx.x, a > 0.f ? a : 0.2f * a);
    mx.y = fmaxf(mx.y, b > 0.f ? b : 0.2f * b);
    mx.z = fmaxf(mx.z, c > 0.f ? c : 0.2f * c);
    mx.w = fmaxf(mx.w, d > 0.f ? d : 0.2f * d);
  }
#pragma unroll
  for (int m = 32; m; m >>= 1) {
    mx.x = fmaxf(mx.x, __shfl_xor(mx.x, m, 64));
    mx.y = fmaxf(mx.y, __shfl_xor(mx.y, m, 64));
    mx.z = fmaxf(mx.z, __shfl_xor(mx.z, m, 64));
    mx.w = fmaxf(mx.w, __shfl_xor(mx.w, m, 64));
  }
  float4 p0 = {0.f, 0.f, 0.f, 0.f}, p1 = {0.f, 0.f, 0.f, 0.f};
  if (s0 >= 0) { p0.x = expf(v0.x - mx.x); p0.y = expf(v0.y - mx.y);
                 p0.z = expf(v0.z - mx.z); p0.w = expf(v0.w - mx.w); }
  if (s1 >= 0) { p1.x = expf(v1.x - mx.x); p1.y = expf(v1.y - mx.y);
                 p1.z = expf(v1.z - mx.z); p1.w = expf(v1.w - mx.w); }
  float4 sm;
  sm.x = p0.x + p1.x; sm.y = p0.y + p1.y; sm.z = p0.z + p1.z; sm.w = p0.w + p1.w;
  for (int e = r0 + 128 + lane; e < r1; e += 64) {
    int s = csr_src[e];
    float4 es = es4[s];
    float a = es.x + ed.x, b = es.y + ed.y, c = es.z + ed.z, d = es.w + ed.w;
    a = a > 0.f ? a : 0.2f * a; b = b > 0.f ? b : 0.2f * b;
    c = c > 0.f ? c : 0.2f * c; d = d > 0.f ? d : 0.2f * d;
    sm.x += expf(a - mx.x); sm.y += expf(b - mx.y);
    sm.z += expf(c - mx.z); sm.w += expf(d - mx.w);
  }
#pragma unroll
  for (int m = 32; m; m >>= 1) {
    sm.x += __shfl_xor(sm.x, m, 64);
    sm.y += __shfl_xor(sm.y, m, 64);
    sm.z += __shfl_xor(sm.z, m, 64);
    sm.w += __shfl_xor(sm.w, m, 64);
  }
  float4 inv;
  inv.x = 1.f / sm.x; inv.y = 1.f / sm.y; inv.z = 1.f / sm.z; inv.w = 1.f / sm.w;

  if (s0 >= 0) {
    float4 w; w.x = p0.x * inv.x; w.y = p0.y * inv.y; w.z = p0.z * inv.z; w.w = p0.w * inv.w;
    wsh[wid][lane] = w; ssh[wid][lane] = s0;
  }
  if (s1 >= 0) {
    float4 w; w.x = p1.x * inv.x; w.y = p1.y * inv.y; w.z = p1.z * inv.z; w.w = p1.w * inv.w;
    wsh[wid][64 + lane] = w; ssh[wid][64 + lane] = s1;
  }
  __builtin_amdgcn_s_waitcnt(0);  // drain lds writes (same-wave RAW)

  // accumulate dims (2*lane, 2*lane+1) per head via float2 gathers
  float2 a0 = {0.f, 0.f}, a1 = {0.f, 0.f}, a2 = {0.f, 0.f}, a3 = {0.f, 0.f};
  int mcap = deg < 128 ? deg : 128;
  for (int i = 0; i < mcap; i++) {
    float4 w = wsh[wid][i];
    int s = ssh[wid][i];
    float2 hv = ((const float2*)(h + s * HID))[lane];
    a0.x = fmaf(w.x, hv.x, a0.x); a0.y = fmaf(w.x, hv.y, a0.y);
    a1.x = fmaf(w.y, hv.x, a1.x); a1.y = fmaf(w.y, hv.y, a1.y);
    a2.x = fmaf(w.z, hv.x, a2.x); a2.y = fmaf(w.z, hv.y, a2.y);
    a3.x = fmaf(w.w, hv.x, a3.x); a3.y = fmaf(w.w, hv.y, a3.y);
  }
  for (int e = r0 + 128; e < r1; e++) {
    int s = csr_src[e];
    float4 es = es4[s];
    float a = es.x + ed.x, b = es.y + ed.y, c = es.z + ed.z, d = es.w + ed.w;
    a = a > 0.f ? a : 0.2f * a; b = b > 0.f ? b : 0.2f * b;
    c = c > 0.f ? c : 0.2f * c; d = d > 0.f ? d : 0.2f * d;
    float w0 = expf(a - mx.x) * inv.x, w1 = expf(b - mx.y) * inv.y;
    float w2 = expf(c - mx.z) * inv.z, w3 = expf(d - mx.w) * inv.w;
    float2 hv = ((const float2*)(h + s * HID))[lane];
    a0.x = fmaf(w0, hv.x, a0.x); a0.y = fmaf(w0, hv.y, a0.y);
    a1.x = fmaf(w1, hv.x, a1.x); a1.y = fmaf(w1, hv.y, a1.y);
    a2.x = fmaf(w2, hv.x, a2.x); a2.y = fmaf(w2, hv.y, a2.y);
    a3.x = fmaf(w3, hv.x, a3.x); a3.y = fmaf(w3, hv.y, a3.y);
  }
  float* ap = agg + idx * 512;
  ((float2*)(ap + 0 * 128))[lane] = a0;
  ((float2*)(ap + 1 * 128))[lane] = a1;
  ((float2*)(ap + 2 * 128))[lane] = a2;
  ((float2*)(ap + 3 * 128))[lane] = a3;
}

// ---------------- out = agg @ Wr /4 + b, LN, relu, residual ----------------
__global__ __launch_bounds__(256) void out_ln_kernel(const float* __restrict__ agg,
    const float* __restrict__ W, const float* __restrict__ bias,
    const float* __restrict__ g, const float* __restrict__ b,
    const float* __restrict__ h_in, float* __restrict__ h_out,
    const int* __restrict__ map) {
  __shared__ float As[32][36];    // transposed A-tile [k][node], padded
  __shared__ float Bs[32][132];   // B-tile [k][dim], padded
  int tid = threadIdx.x;
  int nb = blockIdx.x * 32;
  int tdim = tid & 31;   // dims tdim*4 .. +3
  int tnode = tid >> 5;  // nodes tnode*4 .. +3
  float acc[4][4] = {};
  for (int kb = 0; kb < 512; kb += 32) {
    int hh = kb >> 7;
    int kk0 = kb & 127;
    __syncthreads();
    {
      int n = tid >> 3, kq = tid & 7;
      float4 v = *(const float4*)(agg + (nb + n) * 512 + kb + kq * 4);
      As[kq * 4 + 0][n] = v.x; As[kq * 4 + 1][n] = v.y;
      As[kq * 4 + 2][n] = v.z; As[kq * 4 + 3][n] = v.w;
#pragma unroll
      for (int i = 0; i < 4; i++) {
        int idx4 = tid + i * 256;
        int r = idx4 >> 5, dq = idx4 & 31;
        float4 w = *(const float4*)(W + (kk0 + r) * 512 + hh * 128 + dq * 4);
        *(float4*)&Bs[r][dq * 4] = w;
      }
    }
    __syncthreads();
#pragma unroll
    for (int k = 0; k < 32; k++) {
      float4 av = *(const float4*)&As[k][tnode * 4];
      float4 bv = *(const float4*)&Bs[k][tdim * 4];
      acc[0][0] = fmaf(av.x, bv.x, acc[0][0]); acc[0][1] = fmaf(av.x, bv.y, acc[0][1]);
      acc[0][2] = fmaf(av.x, bv.z, acc[0][2]); acc[0][3] = fmaf(av.x, bv.w, acc[0][3]);
      acc[1][0] = fmaf(av.y, bv.x, acc[1][0]); acc[1][1] = fmaf(av.y, bv.y, acc[1][1]);
      acc[1][2] = fmaf(av.y, bv.z, acc[1][2]); acc[1][3] = fmaf(av.y, bv.w, acc[1][3]);
      acc[2][0] = fmaf(av.z, bv.x, acc[2][0]); acc[2][1] = fmaf(av.z, bv.y, acc[2][1]);
      acc[2][2] = fmaf(av.z, bv.z, acc[2][2]); acc[2][3] = fmaf(av.z, bv.w, acc[2][3]);
      acc[3][0] = fmaf(av.w, bv.x, acc[3][0]); acc[3][1] = fmaf(av.w, bv.y, acc[3][1]);
      acc[3][2] = fmaf(av.w, bv.z, acc[3][2]); acc[3][3] = fmaf(av.w, bv.w, acc[3][3]);
    }
  }
  float4 bias4 = *(const float4*)(bias + tdim * 4);
  float4 g4 = *(const float4*)(g + tdim * 4);
  float4 b4 = *(const float4*)(b + tdim * 4);
#pragma unroll
  for (int i = 0; i < 4; i++) {
    int row = nb + tnode * 4 + i;
    int res = map ? map[row] : row;
    float o0 = acc[i][0] * 0.25f + bias4.x;
    float o1 = acc[i][1] * 0.25f + bias4.y;
    float o2 = acc[i][2] * 0.25f + bias4.z;
    float o3 = acc[i][3] * 0.25f + bias4.w;
    float s1 = o0 + o1 + o2 + o3;
    float s2 = o0 * o0 + o1 * o1 + o2 * o2 + o3 * o3;
#pragma unroll
    for (int m = 1; m < 32; m <<= 1) {
      s1 += __shfl_xor(s1, m, 64);
      s2 += __shfl_xor(s2, m, 64);
    }
    float mu = s1 * 0.0078125f;
    float var = s2 * 0.0078125f - mu * mu;
    float r = 1.0f / sqrtf(var + 1e-5f);
    float4 hi = *(const float4*)(h_in + res * 128 + tdim * 4);
    float4 o;
    o.x = fmaxf((o0 - mu) * r * g4.x + b4.x, 0.f) + hi.x;
    o.y = fmaxf((o1 - mu) * r * g4.y + b4.y, 0.f) + hi.y;
    o.z = fmaxf((o2 - mu) * r * g4.z + b4.z, 0.f) + hi.z;
    o.w = fmaxf((o3 - mu) * r * g4.w + b4.w, 0.f) + hi.w;
    *(float4*)(h_out + row * 128 + tdim * 4) = o;
  }
}

// ---------------- scorer: A = emb@sW1_top + b1, B = emb@sW1_bot ----------------
__global__ __launch_bounds__(128) void ab_kernel(const float* __restrict__ emb,
    const float* __restrict__ sW1, const float* __restrict__ sb1,
    float* __restrict__ As, float* __restrict__ Bs) {
  __shared__ float se[HID];
  int i = blockIdx.x;
  int k = threadIdx.x;
  se[k] = emb[i * HID + k];
  __syncthreads();
  float a = sb1[k], b = 0.f;
  for (int d = 0; d < HID; d++) {
    float e = se[d];
    a = fmaf(e, sW1[d * HID + k], a);
    b = fmaf(e, sW1[(HID + d) * HID + k], b);
  }
  As[i * HID + k] = a;
  Bs[i * HID + k] = b;
}

// ---------------- scorer main: 128 pairs (16i x 8j) x 128 n, 8x8 micro-tile ----------------
// Per k: 4 ds_read_b128 for 64 FMA; T1 reads are 16-lane broadcasts.
// __launch_bounds__(256,2): VGPR budget 256 so the 64-reg accumulator stays resident
// (default heuristic capped at 68 VGPR -> scratch spills, r8 regression 78->92us).
__global__ __launch_bounds__(256, 2) void score_kernel(const float* __restrict__ As,
    const float* __restrict__ Bs, const float* __restrict__ sW2,
    const float* __restrict__ sb2, const float* __restrict__ sW3,
    const float* __restrict__ sb3, float* __restrict__ out) {
  int bx = blockIdx.x, by = blockIdx.y;
  int i0 = bx * 16, j0 = by * 8;
  if (i0 > j0 + 7) return;          // block fully below diagonal
  __shared__ float T1[32][132];     // [k][pair], 128 pairs + pad
  __shared__ float W2s[32][132];    // [k][n]
  int tid = threadIdx.x;
  int tn = tid & 15;    // n-cols: tn*4..+3 and 64+tn*4..+3
  int tp = tid >> 4;    // pair-octet: pairs tp*8..+7 (i = i0+tp, j = j0+0..7)
  // staging: pair sp (0..127), k-half kh (0 or 16)
  int sp = tid >> 1;
  int kh = (tid & 1) * 16;
  const float* arow = As + (i0 + (sp >> 3)) * 128;
  const float* brow = Bs + (j0 + (sp & 7)) * 128;
  float acc[8][8] = {};
  for (int kb = 0; kb < 128; kb += 32) {
    __syncthreads();
#pragma unroll
    for (int q = 0; q < 4; q++) {
      float4 a4 = *(const float4*)(arow + kb + kh + q * 4);
      float4 b4 = *(const float4*)(brow + kb + kh + q * 4);
      T1[kh + q * 4 + 0][sp] = fmaxf(a4.x + b4.x, 0.f);
      T1[kh + q * 4 + 1][sp] = fmaxf(a4.y + b4.y, 0.f);
      T1[kh + q * 4 + 2][sp] = fmaxf(a4.z + b4.z, 0.f);
      T1[kh + q * 4 + 3][sp] = fmaxf(a4.w + b4.w, 0.f);
    }
#pragma unroll
    for (int i = 0; i < 4; i++) {
      int idx4 = tid + i * 256;
      int r = idx4 >> 5, c = (idx4 & 31) * 4;
      *(float4*)&W2s[r][c] = *(const float4*)(sW2 + (kb + r) * 128 + c);
    }
    __syncthreads();
#pragma unroll
    for (int k = 0; k < 32; k++) {
      float4 av0 = *(const float4*)&T1[k][tp * 8];
      float4 av1 = *(const float4*)&T1[k][tp * 8 + 4];
      float4 bv0 = *(const float4*)&W2s[k][tn * 4];
      float4 bv1 = *(const float4*)&W2s[k][64 + tn * 4];
      float a_[8] = {av0.x, av0.y, av0.z, av0.w, av1.x, av1.y, av1.z, av1.w};
      float b_[8] = {bv0.x, bv0.y, bv0.z, bv0.w, bv1.x, bv1.y, bv1.z, bv1.w};
#pragma unroll
      for (int p = 0; p < 8; p++)
#pragma unroll
        for (int q = 0; q < 8; q++)
          acc[p][q] = fmaf(a_[p], b_[q], acc[p][q]);
    }
  }
  // epilogue: relu(t2+b2).w3, reduce over 16 tn-lanes
  float4 b2a = *(const float4*)(sb2 + tn * 4);
  float4 b2b = *(const float4*)(sb2 + 64 + tn * 4);
  float4 w3a = *(const float4*)(sW3 + tn * 4);
  float4 w3b = *(const float4*)(sW3 + 64 + tn * 4);
  float b3v = sb3[0];
#pragma unroll
  for (int pr = 0; pr < 8; pr++) {
    float s = fmaxf(acc[pr][0] + b2a.x, 0.f) * w3a.x
            + fmaxf(acc[pr][1] + b2a.y, 0.f) * w3a.y
            + fmaxf(acc[pr][2] + b2a.z, 0.f) * w3a.z
            + fmaxf(acc[pr][3] + b2a.w, 0.f) * w3a.w
            + fmaxf(acc[pr][4] + b2b.x, 0.f) * w3b.x
            + fmaxf(acc[pr][5] + b2b.y, 0.f) * w3b.y
            + fmaxf(acc[pr][6] + b2b.z, 0.f) * w3b.z
            + fmaxf(acc[pr][7] + b2b.w, 0.f) * w3b.w;
#pragma unroll
    for (int m = 1; m < 16; m <<= 1) s += __shfl_xor(s, m, 64);
    if (tn == 0) {
      int p = tp * 8 + pr;                 // pair 0..127
      int i = i0 + (p >> 3), j = j0 + (p & 7);
      if (i < j) {
        float v = s + b3v;
        out[i * 512 + j] = v;
        out[j * 512 + i] = v;
      } else if (i == j) {
        out[i * 512 + j] = 0.f;
      }
    }
  }
}

// ---------------- launch ----------------
extern "C" void kernel_launch(void* const* d_in, const int* in_sizes, int n_in,
                              void* d_out, int out_size, void* d_ws, size_t ws_size,
                              hipStream_t stream) {
  const float* x       = (const float*)d_in[0];
  const int*   ei      = (const int*)d_in[1];
  const int*   odd     = (const int*)d_in[2];
  const float* node_W  = (const float*)d_in[3];
  const float* node_b  = (const float*)d_in[4];
  const float* gat_W   = (const float*)d_in[5];
  const float* att_src = (const float*)d_in[6];
  const float* att_dst = (const float*)d_in[7];
  const float* gat_b   = (const float*)d_in[8];
  const float* ln_g    = (const float*)d_in[9];
  const float* ln_b    = (const float*)d_in[10];
  const float* sW1     = (const float*)d_in[11];
  const float* sb1     = (const float*)d_in[12];
  const float* sW2     = (const float*)d_in[13];
  const float* sb2     = (const float*)d_in[14];
  const float* sW3     = (const float*)d_in[15];
  const float* sb3     = (const float*)d_in[16];
  float* out = (float*)d_out;

  float* f = (float*)d_ws;
  float* hA  = f; f += NODES * HID;
  float* hB  = f; f += NODES * HID;
  float* agg = f; f += NODES * 512;
  float* e_s = f; f += NODES * 4;
  float* e_d = f; f += NODES * 4;
  float* c_s = f; f += 512;
  float* c_d = f; f += 512;
  float* Asb = f; f += NODD * HID;
  float* Bsb = f; f += NODD * HID;
  float* emb = f; f += NODD * HID;
  int* cnt       = (int*)f;
  int* row_start = cnt + NODES;
  int* pos       = row_start + NODES + 1;
  int* csr       = pos + NODES;

  hipMemsetAsync(cnt, 0, NODES * sizeof(int), stream);
  hist_kernel<<<(NTOT + 255) / 256, 256, 0, stream>>>(ei, cnt);
  scan_kernel<<<1, 1024, 0, stream>>>(cnt, row_start, pos);
  scatter_kernel<<<(NTOT + 255) / 256, 256, 0, stream>>>(ei, pos, csr);
  node_enc_kernel<<<(NODES * HID + 255) / 256, 256, 0, stream>>>(x, node_W, node_b, hA);

  const float* hc = hA;
  float* hn = hB;
  // layers 0,1: full-node
  for (int l = 0; l < 2; l++) {
    att_c_kernel<<<HEADS, 128, 0, stream>>>(gat_W + l * HID * 512,
                                            att_src + l * 512, att_dst + l * 512, c_s, c_d);
    e_kernel<<<NODES / 4, 256, 0, stream>>>(hc, c_s, c_d, e_s, e_d);
    agg_kernel<<<NODES / 4, 256, 0, stream>>>(hc, e_s, e_d, row_start, csr, agg, nullptr);
    out_ln_kernel<<<NODES / 32, 256, 0, stream>>>(agg, gat_W + l * HID * 512,
                                                  gat_b + l * HID, ln_g + l * HID,
                                                  ln_b + l * HID, hc, hn, nullptr);
    float* t = (float*)hc; hc = hn; hn = t;
  }
  // layer 2: only odd vertices need output
  {
    const int l = 2;
    att_c_kernel<<<HEADS, 128, 0, stream>>>(gat_W + l * HID * 512,
                                            att_src + l * 512, att_dst + l * 512, c_s, c_d);
    e_kernel<<<NODES / 4, 256, 0, stream>>>(hc, c_s, c_d, e_s, e_d);
    agg_kernel<<<NODD / 4, 256, 0, stream>>>(hc, e_s, e_d, row_start, csr, agg, odd);
    out_ln_kernel<<<NODD / 32, 256, 0, stream>>>(agg, gat_W + l * HID * 512,
                                                 gat_b + l * HID, ln_g + l * HID,
                                                 ln_b + l * HID, hc, emb, odd);
  }
  ab_kernel<<<NODD, 128, 0, stream>>>(emb, sW1, sb1, Asb, Bsb);
  score_kernel<<<dim3(32, 64), 256, 0, stream>>>(Asb, Bsb, sW2, sb2, sW3, sb3, out);
}

// Round 10
// 458.119 us; speedup vs baseline: 1.0878x; 1.0878x over previous
//
#include <hip/hip_runtime.h>

#define HID 128
#define HEADS 4
#define NODES 20000
#define NEDGE 320000
#define NTOT (NEDGE + NODES)
#define NODD 512

// ---------------- CSR build ----------------
__global__ void hist_kernel(const int* __restrict__ ei, int* __restrict__ cnt) {
  int e = blockIdx.x * blockDim.x + threadIdx.x;
  if (e >= NTOT) return;
  int d = (e < NEDGE) ? ei[NEDGE + e] : (e - NEDGE);
  atomicAdd(&cnt[d], 1);
}

// 4 elements/thread (int4): 5 chunk iterations instead of 20.
__global__ void scan_kernel(const int* __restrict__ cnt, int* __restrict__ row_start,
                            int* __restrict__ pos) {
  __shared__ int wsum[16];
  __shared__ int s_carry;
  int t = threadIdx.x;
  int lane = t & 63, wid = t >> 6;
  if (t == 0) s_carry = 0;
  __syncthreads();
  const int4* cnt4 = (const int4*)cnt;
  for (int base4 = 0; base4 < NODES / 4; base4 += 1024) {
    int idx4 = base4 + t;
    int4 v = {0, 0, 0, 0};
    if (idx4 < NODES / 4) v = cnt4[idx4];
    int s0 = v.x, s1 = s0 + v.y, s2 = s1 + v.z, s3 = s2 + v.w;
    int x = s3;
    for (int off = 1; off < 64; off <<= 1) {
      int y = __shfl_up(x, off, 64);
      if (lane >= off) x += y;
    }
    if (lane == 63) wsum[wid] = x;
    __syncthreads();
    if (wid == 0) {
      int w = (lane < 16) ? wsum[lane] : 0;
      for (int off = 1; off < 16; off <<= 1) {
        int y = __shfl_up(w, off, 64);
        if (lane >= off) w += y;
      }
      if (lane < 16) wsum[lane] = w;
    }
    __syncthreads();
    int waveoff = (wid == 0) ? 0 : wsum[wid - 1];
    int incl = s_carry + waveoff + x;   // inclusive through this thread's 4 elems
    int excl = incl - s3;               // exclusive before elem 0
    if (idx4 < NODES / 4) {
      int o = idx4 * 4;
      row_start[o] = excl;          pos[o] = excl;
      row_start[o + 1] = excl + s0; pos[o + 1] = excl + s0;
      row_start[o + 2] = excl + s1; pos[o + 2] = excl + s1;
      row_start[o + 3] = excl + s2; pos[o + 3] = excl + s2;
    }
    __syncthreads();
    if (t == 1023) s_carry = incl;
    __syncthreads();
  }
  if (t == 0) row_start[NODES] = s_carry;
}

__global__ void scatter_kernel(const int* __restrict__ ei, int* __restrict__ pos,
                               int* __restrict__ csr_src) {
  int e = blockIdx.x * blockDim.x + threadIdx.x;
  if (e >= NTOT) return;
  int s, d;
  if (e < NEDGE) { s = ei[e]; d = ei[NEDGE + e]; } else { s = e - NEDGE; d = s; }
  int p = atomicAdd(&pos[d], 1);
  csr_src[p] = s;
}

// ---------------- node encoder ----------------
__global__ void node_enc_kernel(const float* __restrict__ x, const float* __restrict__ W,
                                const float* __restrict__ b, float* __restrict__ h) {
  int idx = blockIdx.x * blockDim.x + threadIdx.x;
  if (idx >= NODES * HID) return;
  int n = idx >> 7, d = idx & 127;
  const float* xr = x + n * 5;
  float acc = b[d];
#pragma unroll
  for (int k = 0; k < 5; k++) acc = fmaf(xr[k], W[k * HID + d], acc);
  h[idx] = fmaxf(acc, 0.f);
}

// ---------------- per-layer attention coefs ----------------
__global__ void att_c_kernel(const float* __restrict__ W, const float* __restrict__ a_src,
                             const float* __restrict__ a_dst, float* __restrict__ c_src,
                             float* __restrict__ c_dst) {
  int h = blockIdx.x;        // 0..3
  int k = threadIdx.x;       // 0..127
  const float* wr = W + k * (HEADS * HID) + h * HID;
  const float* as = a_src + h * HID;
  const float* ad = a_dst + h * HID;
  float s1 = 0.f, s2 = 0.f;
  for (int d = 0; d < HID; d++) {
    float w = wr[d];
    s1 = fmaf(w, as[d], s1);
    s2 = fmaf(w, ad[d], s2);
  }
  c_src[h * HID + k] = s1;
  c_dst[h * HID + k] = s2;
}

// e_src[n,h] = h[n,:] . c_src[h,:]   (4 nodes per block, one wave each)
__global__ __launch_bounds__(256) void e_kernel(const float* __restrict__ h,
    const float* __restrict__ c_src, const float* __restrict__ c_dst,
    float* __restrict__ e_src, float* __restrict__ e_dst) {
  int lane = threadIdx.x & 63;
  int wid = threadIdx.x >> 6;
  int n = blockIdx.x * 4 + wid;
  float v0 = h[n * HID + lane];
  float v1 = h[n * HID + 64 + lane];
#pragma unroll
  for (int hh = 0; hh < HEADS; hh++) {
    float p = v0 * c_src[hh * HID + lane] + v1 * c_src[hh * HID + 64 + lane];
#pragma unroll
    for (int m = 32; m; m >>= 1) p += __shfl_xor(p, m, 64);
    if (lane == 0) e_src[n * HEADS + hh] = p;
    float q = v0 * c_dst[hh * HID + lane] + v1 * c_dst[hh * HID + 64 + lane];
#pragma unroll
    for (int m = 32; m; m >>= 1) q += __shfl_xor(q, m, 64);
    if (lane == 0) e_dst[n * HEADS + hh] = q;
  }
}

// ---------------- per-dst softmax + aggregation of raw h ----------------
// 4 nodes per block (one wave each). map!=null: node = map[idx], compact output row.
// Gather loop unrolled x2 with dual accumulators for load-latency overlap.
__global__ __launch_bounds__(256) void agg_kernel(const float* __restrict__ h,
    const float* __restrict__ e_src, const float* __restrict__ e_dst,
    const int* __restrict__ row_start, const int* __restrict__ csr_src,
    float* __restrict__ agg, const int* __restrict__ map) {
  __shared__ float4 wsh[4][128];
  __shared__ int ssh[4][128];
  int lane = threadIdx.x & 63;
  int wid = threadIdx.x >> 6;
  int idx = blockIdx.x * 4 + wid;
  int n = map ? map[idx] : idx;
  int r0 = row_start[n], r1 = row_start[n + 1];
  int deg = r1 - r0;
  const float4* es4 = (const float4*)e_src;
  float4 ed = ((const float4*)e_dst)[n];

  int s0 = -1, s1 = -1;
  float4 v0 = {-1e30f, -1e30f, -1e30f, -1e30f};
  float4 v1 = {-1e30f, -1e30f, -1e30f, -1e30f};
  {
    int e = r0 + lane;
    if (e < r1) {
      s0 = csr_src[e];
      float4 es = es4[s0];
      float a = es.x + ed.x, b = es.y + ed.y, c = es.z + ed.z, d = es.w + ed.w;
      v0.x = a > 0.f ? a : 0.2f * a; v0.y = b > 0.f ? b : 0.2f * b;
      v0.z = c > 0.f ? c : 0.2f * c; v0.w = d > 0.f ? d : 0.2f * d;
    }
    e = r0 + 64 + lane;
    if (e < r1) {
      s1 = csr_src[e];
      float4 es = es4[s1];
      float a = es.x + ed.x, b = es.y + ed.y, c = es.z + ed.z, d = es.w + ed.w;
      v1.x = a > 0.f ? a : 0.2f * a; v1.y = b > 0.f ? b : 0.2f * b;
      v1.z = c > 0.f ? c : 0.2f * c; v1.w = d > 0.f ? d : 0.2f * d;
    }
  }
  float4 mx;
  mx.x = fmaxf(v0.x, v1.x); mx.y = fmaxf(v0.y, v1.y);
  mx.z = fmaxf(v0.z, v1.z); mx.w = fmaxf(v0.w, v1.w);
  for (int e = r0 + 128 + lane; e < r1; e += 64) {
    int s = csr_src[e];
    float4 es = es4[s];
    float a = es.x + ed.x, b = es.y + ed.y, c = es.z + ed.z, d = es.w + ed.w;
    mx.x = fmaxf(mx.x, a > 0.f ? a : 0.2f * a);
    mx.y = fmaxf(mx.y, b > 0.f ? b : 0.2f * b);
    mx.z = fmaxf(mx.z, c > 0.f ? c : 0.2f * c);
    mx.w = fmaxf(mx.w, d > 0.f ? d : 0.2f * d);
  }
#pragma unroll
  for (int m = 32; m; m >>= 1) {
    mx.x = fmaxf(mx.x, __shfl_xor(mx.x, m, 64));
    mx.y = fmaxf(mx.y, __shfl_xor(mx.y, m, 64));
    mx.z = fmaxf(mx.z, __shfl_xor(mx.z, m, 64));
    mx.w = fmaxf(mx.w, __shfl_xor(mx.w, m, 64));
  }
  float4 p0 = {0.f, 0.f, 0.f, 0.f}, p1 = {0.f, 0.f, 0.f, 0.f};
  if (s0 >= 0) { p0.x = expf(v0.x - mx.x); p0.y = expf(v0.y - mx.y);
                 p0.z = expf(v0.z - mx.z); p0.w = expf(v0.w - mx.w); }
  if (s1 >= 0) { p1.x = expf(v1.x - mx.x); p1.y = expf(v1.y - mx.y);
                 p1.z = expf(v1.z - mx.z); p1.w = expf(v1.w - mx.w); }
  float4 sm;
  sm.x = p0.x + p1.x; sm.y = p0.y + p1.y; sm.z = p0.z + p1.z; sm.w = p0.w + p1.w;
  for (int e = r0 + 128 + lane; e < r1; e += 64) {
    int s = csr_src[e];
    float4 es = es4[s];
    float a = es.x + ed.x, b = es.y + ed.y, c = es.z + ed.z, d = es.w + ed.w;
    a = a > 0.f ? a : 0.2f * a; b = b > 0.f ? b : 0.2f * b;
    c = c > 0.f ? c : 0.2f * c; d = d > 0.f ? d : 0.2f * d;
    sm.x += expf(a - mx.x); sm.y += expf(b - mx.y);
    sm.z += expf(c - mx.z); sm.w += expf(d - mx.w);
  }
#pragma unroll
  for (int m = 32; m; m >>= 1) {
    sm.x += __shfl_xor(sm.x, m, 64);
    sm.y += __shfl_xor(sm.y, m, 64);
    sm.z += __shfl_xor(sm.z, m, 64);
    sm.w += __shfl_xor(sm.w, m, 64);
  }
  float4 inv;
  inv.x = 1.f / sm.x; inv.y = 1.f / sm.y; inv.z = 1.f / sm.z; inv.w = 1.f / sm.w;

  if (s0 >= 0) {
    float4 w; w.x = p0.x * inv.x; w.y = p0.y * inv.y; w.z = p0.z * inv.z; w.w = p0.w * inv.w;
    wsh[wid][lane] = w; ssh[wid][lane] = s0;
  }
  if (s1 >= 0) {
    float4 w; w.x = p1.x * inv.x; w.y = p1.y * inv.y; w.z = p1.z * inv.z; w.w = p1.w * inv.w;
    wsh[wid][64 + lane] = w; ssh[wid][64 + lane] = s1;
  }
  __builtin_amdgcn_s_waitcnt(0);  // drain lds writes (same-wave RAW)

  // accumulate dims (2*lane, 2*lane+1) per head; 2x unrolled, dual accumulators
  float2 a0 = {0.f, 0.f}, a1 = {0.f, 0.f}, a2 = {0.f, 0.f}, a3 = {0.f, 0.f};
  float2 b0 = {0.f, 0.f}, b1 = {0.f, 0.f}, b2 = {0.f, 0.f}, b3 = {0.f, 0.f};
  int mcap = deg < 128 ? deg : 128;
  int i = 0;
  for (; i + 2 <= mcap; i += 2) {
    float4 wA = wsh[wid][i];     int sA = ssh[wid][i];
    float4 wB = wsh[wid][i + 1]; int sB = ssh[wid][i + 1];
    float2 hA = ((const float2*)(h + sA * HID))[lane];
    float2 hB = ((const float2*)(h + sB * HID))[lane];
    a0.x = fmaf(wA.x, hA.x, a0.x); a0.y = fmaf(wA.x, hA.y, a0.y);
    a1.x = fmaf(wA.y, hA.x, a1.x); a1.y = fmaf(wA.y, hA.y, a1.y);
    a2.x = fmaf(wA.z, hA.x, a2.x); a2.y = fmaf(wA.z, hA.y, a2.y);
    a3.x = fmaf(wA.w, hA.x, a3.x); a3.y = fmaf(wA.w, hA.y, a3.y);
    b0.x = fmaf(wB.x, hB.x, b0.x); b0.y = fmaf(wB.x, hB.y, b0.y);
    b1.x = fmaf(wB.y, hB.x, b1.x); b1.y = fmaf(wB.y, hB.y, b1.y);
    b2.x = fmaf(wB.z, hB.x, b2.x); b2.y = fmaf(wB.z, hB.y, b2.y);
    b3.x = fmaf(wB.w, hB.x, b3.x); b3.y = fmaf(wB.w, hB.y, b3.y);
  }
  if (i < mcap) {
    float4 w = wsh[wid][i];
    int s = ssh[wid][i];
    float2 hv = ((const float2*)(h + s * HID))[lane];
    a0.x = fmaf(w.x, hv.x, a0.x); a0.y = fmaf(w.x, hv.y, a0.y);
    a1.x = fmaf(w.y, hv.x, a1.x); a1.y = fmaf(w.y, hv.y, a1.y);
    a2.x = fmaf(w.z, hv.x, a2.x); a2.y = fmaf(w.z, hv.y, a2.y);
    a3.x = fmaf(w.w, hv.x, a3.x); a3.y = fmaf(w.w, hv.y, a3.y);
  }
  a0.x += b0.x; a0.y += b0.y; a1.x += b1.x; a1.y += b1.y;
  a2.x += b2.x; a2.y += b2.y; a3.x += b3.x; a3.y += b3.y;
  for (int e = r0 + 128; e < r1; e++) {
    int s = csr_src[e];
    float4 es = es4[s];
    float a = es.x + ed.x, b = es.y + ed.y, c = es.z + ed.z, d = es.w + ed.w;
    a = a > 0.f ? a : 0.2f * a; b = b > 0.f ? b : 0.2f * b;
    c = c > 0.f ? c : 0.2f * c; d = d > 0.f ? d : 0.2f * d;
    float w0 = expf(a - mx.x) * inv.x, w1 = expf(b - mx.y) * inv.y;
    float w2 = expf(c - mx.z) * inv.z, w3 = expf(d - mx.w) * inv.w;
    float2 hv = ((const float2*)(h + s * HID))[lane];
    a0.x = fmaf(w0, hv.x, a0.x); a0.y = fmaf(w0, hv.y, a0.y);
    a1.x = fmaf(w1, hv.x, a1.x); a1.y = fmaf(w1, hv.y, a1.y);
    a2.x = fmaf(w2, hv.x, a2.x); a2.y = fmaf(w2, hv.y, a2.y);
    a3.x = fmaf(w3, hv.x, a3.x); a3.y = fmaf(w3, hv.y, a3.y);
  }
  float* ap = agg + idx * 512;
  ((float2*)(ap + 0 * 128))[lane] = a0;
  ((float2*)(ap + 1 * 128))[lane] = a1;
  ((float2*)(ap + 2 * 128))[lane] = a2;
  ((float2*)(ap + 3 * 128))[lane] = a3;
}

// ---------------- out = agg @ Wr /4 + b, LN, relu, residual ----------------
__global__ __launch_bounds__(256) void out_ln_kernel(const float* __restrict__ agg,
    const float* __restrict__ W, const float* __restrict__ bias,
    const float* __restrict__ g, const float* __restrict__ b,
    const float* __restrict__ h_in, float* __restrict__ h_out,
    const int* __restrict__ map) {
  __shared__ float As[32][36];    // transposed A-tile [k][node], padded
  __shared__ float Bs[32][132];   // B-tile [k][dim], padded
  int tid = threadIdx.x;
  int nb = blockIdx.x * 32;
  int tdim = tid & 31;   // dims tdim*4 .. +3
  int tnode = tid >> 5;  // nodes tnode*4 .. +3
  float acc[4][4] = {};
  for (int kb = 0; kb < 512; kb += 32) {
    int hh = kb >> 7;
    int kk0 = kb & 127;
    __syncthreads();
    {
      int n = tid >> 3, kq = tid & 7;
      float4 v = *(const float4*)(agg + (nb + n) * 512 + kb + kq * 4);
      As[kq * 4 + 0][n] = v.x; As[kq * 4 + 1][n] = v.y;
      As[kq * 4 + 2][n] = v.z; As[kq * 4 + 3][n] = v.w;
#pragma unroll
      for (int i = 0; i < 4; i++) {
        int idx4 = tid + i * 256;
        int r = idx4 >> 5, dq = idx4 & 31;
        float4 w = *(const float4*)(W + (kk0 + r) * 512 + hh * 128 + dq * 4);
        *(float4*)&Bs[r][dq * 4] = w;
      }
    }
    __syncthreads();
#pragma unroll
    for (int k = 0; k < 32; k++) {
      float4 av = *(const float4*)&As[k][tnode * 4];
      float4 bv = *(const float4*)&Bs[k][tdim * 4];
      acc[0][0] = fmaf(av.x, bv.x, acc[0][0]); acc[0][1] = fmaf(av.x, bv.y, acc[0][1]);
      acc[0][2] = fmaf(av.x, bv.z, acc[0][2]); acc[0][3] = fmaf(av.x, bv.w, acc[0][3]);
      acc[1][0] = fmaf(av.y, bv.x, acc[1][0]); acc[1][1] = fmaf(av.y, bv.y, acc[1][1]);
      acc[1][2] = fmaf(av.y, bv.z, acc[1][2]); acc[1][3] = fmaf(av.y, bv.w, acc[1][3]);
      acc[2][0] = fmaf(av.z, bv.x, acc[2][0]); acc[2][1] = fmaf(av.z, bv.y, acc[2][1]);
      acc[2][2] = fmaf(av.z, bv.z, acc[2][2]); acc[2][3] = fmaf(av.z, bv.w, acc[2][3]);
      acc[3][0] = fmaf(av.w, bv.x, acc[3][0]); acc[3][1] = fmaf(av.w, bv.y, acc[3][1]);
      acc[3][2] = fmaf(av.w, bv.z, acc[3][2]); acc[3][3] = fmaf(av.w, bv.w, acc[3][3]);
    }
  }
  float4 bias4 = *(const float4*)(bias + tdim * 4);
  float4 g4 = *(const float4*)(g + tdim * 4);
  float4 b4 = *(const float4*)(b + tdim * 4);
#pragma unroll
  for (int i = 0; i < 4; i++) {
    int row = nb + tnode * 4 + i;
    int res = map ? map[row] : row;
    float o0 = acc[i][0] * 0.25f + bias4.x;
    float o1 = acc[i][1] * 0.25f + bias4.y;
    float o2 = acc[i][2] * 0.25f + bias4.z;
    float o3 = acc[i][3] * 0.25f + bias4.w;
    float s1 = o0 + o1 + o2 + o3;
    float s2 = o0 * o0 + o1 * o1 + o2 * o2 + o3 * o3;
#pragma unroll
    for (int m = 1; m < 32; m <<= 1) {
      s1 += __shfl_xor(s1, m, 64);
      s2 += __shfl_xor(s2, m, 64);
    }
    float mu = s1 * 0.0078125f;
    float var = s2 * 0.0078125f - mu * mu;
    float r = 1.0f / sqrtf(var + 1e-5f);
    float4 hi = *(const float4*)(h_in + res * 128 + tdim * 4);
    float4 o;
    o.x = fmaxf((o0 - mu) * r * g4.x + b4.x, 0.f) + hi.x;
    o.y = fmaxf((o1 - mu) * r * g4.y + b4.y, 0.f) + hi.y;
    o.z = fmaxf((o2 - mu) * r * g4.z + b4.z, 0.f) + hi.z;
    o.w = fmaxf((o3 - mu) * r * g4.w + b4.w, 0.f) + hi.w;
    *(float4*)(h_out + row * 128 + tdim * 4) = o;
  }
}

// ---------------- scorer: A = emb@sW1_top + b1, B = emb@sW1_bot ----------------
__global__ __launch_bounds__(128) void ab_kernel(const float* __restrict__ emb,
    const float* __restrict__ sW1, const float* __restrict__ sb1,
    float* __restrict__ As, float* __restrict__ Bs) {
  __shared__ float se[HID];
  int i = blockIdx.x;
  int k = threadIdx.x;
  se[k] = emb[i * HID + k];
  __syncthreads();
  float a = sb1[k], b = 0.f;
  for (int d = 0; d < HID; d++) {
    float e = se[d];
    a = fmaf(e, sW1[d * HID + k], a);
    b = fmaf(e, sW1[(HID + d) * HID + k], b);
  }
  As[i * HID + k] = a;
  Bs[i * HID + k] = b;
}

// ---------------- scorer main: 64 pairs (8i x 8j) x 128 n, 4x8 micro-tile ----------------
// (r7 config: bench-proven 78us / VGPR 40 / occ 27%. 8x8 regressed: allocator pins
// VGPR at 68 and shuffles the 64-reg accumulator through AGPR/scratch.)
__global__ __launch_bounds__(256) void score_kernel(const float* __restrict__ As,
    const float* __restrict__ Bs, const float* __restrict__ sW2,
    const float* __restrict__ sb2, const float* __restrict__ sW3,
    const float* __restrict__ sb3, float* __restrict__ out) {
  int bx = blockIdx.x, by = blockIdx.y;
  if (bx > by) return;              // block fully below diagonal
  int i0 = bx * 8, j0 = by * 8;
  __shared__ float T1[32][68];      // [k][pair]
  __shared__ float W2s[32][132];    // [k][n]
  int tid = threadIdx.x;
  int tn = tid & 15;    // n-cols: tn*4..+3 and 64+tn*4..+3
  int tp = tid >> 4;    // pairs tp*4..+3 (tp 0..15)
  int sp = tid >> 2;
  int kq = (tid & 3) * 8;
  const float* arow = As + (i0 + (sp >> 3)) * 128;
  const float* brow = Bs + (j0 + (sp & 7)) * 128;
  float acc[4][8] = {};
  for (int kb = 0; kb < 128; kb += 32) {
    __syncthreads();
    {
      float4 a0 = *(const float4*)(arow + kb + kq);
      float4 b0 = *(const float4*)(brow + kb + kq);
      float4 a1 = *(const float4*)(arow + kb + kq + 4);
      float4 b1 = *(const float4*)(brow + kb + kq + 4);
      T1[kq + 0][sp] = fmaxf(a0.x + b0.x, 0.f);
      T1[kq + 1][sp] = fmaxf(a0.y + b0.y, 0.f);
      T1[kq + 2][sp] = fmaxf(a0.z + b0.z, 0.f);
      T1[kq + 3][sp] = fmaxf(a0.w + b0.w, 0.f);
      T1[kq + 4][sp] = fmaxf(a1.x + b1.x, 0.f);
      T1[kq + 5][sp] = fmaxf(a1.y + b1.y, 0.f);
      T1[kq + 6][sp] = fmaxf(a1.z + b1.z, 0.f);
      T1[kq + 7][sp] = fmaxf(a1.w + b1.w, 0.f);
#pragma unroll
      for (int i = 0; i < 4; i++) {
        int idx4 = tid + i * 256;
        int r = idx4 >> 5, c = (idx4 & 31) * 4;
        float4 w = *(const float4*)(sW2 + (kb + r) * 128 + c);
        *(float4*)&W2s[r][c] = w;
      }
    }
    __syncthreads();
#pragma unroll
    for (int k = 0; k < 32; k++) {
      float4 av  = *(const float4*)&T1[k][tp * 4];
      float4 bv0 = *(const float4*)&W2s[k][tn * 4];
      float4 bv1 = *(const float4*)&W2s[k][64 + tn * 4];
#pragma unroll
      for (int p = 0; p < 4; p++) {
        float a = (p == 0) ? av.x : (p == 1) ? av.y : (p == 2) ? av.z : av.w;
        acc[p][0] = fmaf(a, bv0.x, acc[p][0]); acc[p][1] = fmaf(a, bv0.y, acc[p][1]);
        acc[p][2] = fmaf(a, bv0.z, acc[p][2]); acc[p][3] = fmaf(a, bv0.w, acc[p][3]);
        acc[p][4] = fmaf(a, bv1.x, acc[p][4]); acc[p][5] = fmaf(a, bv1.y, acc[p][5]);
        acc[p][6] = fmaf(a, bv1.z, acc[p][6]); acc[p][7] = fmaf(a, bv1.w, acc[p][7]);
      }
    }
  }
  // epilogue: relu(t2+b2).w3, reduce over 16 tn-lanes
  float4 b2a = *(const float4*)(sb2 + tn * 4);
  float4 b2b = *(const float4*)(sb2 + 64 + tn * 4);
  float4 w3a = *(const float4*)(sW3 + tn * 4);
  float4 w3b = *(const float4*)(sW3 + 64 + tn * 4);
  float b3v = sb3[0];
#pragma unroll
  for (int pr = 0; pr < 4; pr++) {
    float s = fmaxf(acc[pr][0] + b2a.x, 0.f) * w3a.x
            + fmaxf(acc[pr][1] + b2a.y, 0.f) * w3a.y
            + fmaxf(acc[pr][2] + b2a.z, 0.f) * w3a.z
            + fmaxf(acc[pr][3] + b2a.w, 0.f) * w3a.w
            + fmaxf(acc[pr][4] + b2b.x, 0.f) * w3b.x
            + fmaxf(acc[pr][5] + b2b.y, 0.f) * w3b.y
            + fmaxf(acc[pr][6] + b2b.z, 0.f) * w3b.z
            + fmaxf(acc[pr][7] + b2b.w, 0.f) * w3b.w;
#pragma unroll
    for (int m = 1; m < 16; m <<= 1) s += __shfl_xor(s, m, 64);
    if (tn == 0) {
      int p = tp * 4 + pr;
      int i = i0 + (p >> 3), j = j0 + (p & 7);
      if (i < j) {
        float v = s + b3v;
        out[i * 512 + j] = v;
        out[j * 512 + i] = v;
      } else if (i == j) {
        out[i * 512 + j] = 0.f;
      }
    }
  }
}

// ---------------- launch ----------------
extern "C" void kernel_launch(void* const* d_in, const int* in_sizes, int n_in,
                              void* d_out, int out_size, void* d_ws, size_t ws_size,
                              hipStream_t stream) {
  const float* x       = (const float*)d_in[0];
  const int*   ei      = (const int*)d_in[1];
  const int*   odd     = (const int*)d_in[2];
  const float* node_W  = (const float*)d_in[3];
  const float* node_b  = (const float*)d_in[4];
  const float* gat_W   = (const float*)d_in[5];
  const float* att_src = (const float*)d_in[6];
  const float* att_dst = (const float*)d_in[7];
  const float* gat_b   = (const float*)d_in[8];
  const float* ln_g    = (const float*)d_in[9];
  const float* ln_b    = (const float*)d_in[10];
  const float* sW1     = (const float*)d_in[11];
  const float* sb1     = (const float*)d_in[12];
  const float* sW2     = (const float*)d_in[13];
  const float* sb2     = (const float*)d_in[14];
  const float* sW3     = (const float*)d_in[15];
  const float* sb3     = (const float*)d_in[16];
  float* out = (float*)d_out;

  float* f = (float*)d_ws;
  float* hA  = f; f += NODES * HID;
  float* hB  = f; f += NODES * HID;
  float* agg = f; f += NODES * 512;
  float* e_s = f; f += NODES * 4;
  float* e_d = f; f += NODES * 4;
  float* c_s = f; f += 512;
  float* c_d = f; f += 512;
  float* Asb = f; f += NODD * HID;
  float* Bsb = f; f += NODD * HID;
  float* emb = f; f += NODD * HID;
  int* cnt       = (int*)f;
  int* row_start = cnt + NODES;
  int* pos       = row_start + NODES + 1;
  int* csr       = pos + NODES;

  hipMemsetAsync(cnt, 0, NODES * sizeof(int), stream);
  hist_kernel<<<(NTOT + 255) / 256, 256, 0, stream>>>(ei, cnt);
  scan_kernel<<<1, 1024, 0, stream>>>(cnt, row_start, pos);
  scatter_kernel<<<(NTOT + 255) / 256, 256, 0, stream>>>(ei, pos, csr);
  node_enc_kernel<<<(NODES * HID + 255) / 256, 256, 0, stream>>>(x, node_W, node_b, hA);

  const float* hc = hA;
  float* hn = hB;
  // layers 0,1: full-node
  for (int l = 0; l < 2; l++) {
    att_c_kernel<<<HEADS, 128, 0, stream>>>(gat_W + l * HID * 512,
                                            att_src + l * 512, att_dst + l * 512, c_s, c_d);
    e_kernel<<<NODES / 4, 256, 0, stream>>>(hc, c_s, c_d, e_s, e_d);
    agg_kernel<<<NODES / 4, 256, 0, stream>>>(hc, e_s, e_d, row_start, csr, agg, nullptr);
    out_ln_kernel<<<NODES / 32, 256, 0, stream>>>(agg, gat_W + l * HID * 512,
                                                  gat_b + l * HID, ln_g + l * HID,
                                                  ln_b + l * HID, hc, hn, nullptr);
    float* t = (float*)hc; hc = hn; hn = t;
  }
  // layer 2: only odd vertices need output
  {
    const int l = 2;
    att_c_kernel<<<HEADS, 128, 0, stream>>>(gat_W + l * HID * 512,
                                            att_src + l * 512, att_dst + l * 512, c_s, c_d);
    e_kernel<<<NODES / 4, 256, 0, stream>>>(hc, c_s, c_d, e_s, e_d);
    agg_kernel<<<NODD / 4, 256, 0, stream>>>(hc, e_s, e_d, row_start, csr, agg, odd);
    out_ln_kernel<<<NODD / 32, 256, 0, stream>>>(agg, gat_W + l * HID * 512,
                                                 gat_b + l * HID, ln_g + l * HID,
                                                 ln_b + l * HID, hc, emb, odd);
  }
  ab_kernel<<<NODD, 128, 0, stream>>>(emb, sW1, sb1, Asb, Bsb);
  score_kernel<<<dim3(64, 64), 256, 0, stream>>>(Asb, Bsb, sW2, sb2, sW3, sb3, out);
}

// Round 12
// 426.510 us; speedup vs baseline: 1.1684x; 1.0741x over previous
//
#include <hip/hip_runtime.h>

#define HID 128
#define HEADS 4
#define NODES 20000
#define NEDGE 320000
#define NTOT (NEDGE + NODES)
#define NODD 512

// ---------------- CSR build ----------------
__global__ void hist_kernel(const int* __restrict__ ei, int* __restrict__ cnt) {
  int e = blockIdx.x * blockDim.x + threadIdx.x;
  if (e >= NTOT) return;
  int d = (e < NEDGE) ? ei[NEDGE + e] : (e - NEDGE);
  atomicAdd(&cnt[d], 1);
}

// 4 elements/thread (int4): 5 chunk iterations instead of 20.
__global__ void scan_kernel(const int* __restrict__ cnt, int* __restrict__ row_start,
                            int* __restrict__ pos) {
  __shared__ int wsum[16];
  __shared__ int s_carry;
  int t = threadIdx.x;
  int lane = t & 63, wid = t >> 6;
  if (t == 0) s_carry = 0;
  __syncthreads();
  const int4* cnt4 = (const int4*)cnt;
  for (int base4 = 0; base4 < NODES / 4; base4 += 1024) {
    int idx4 = base4 + t;
    int4 v = {0, 0, 0, 0};
    if (idx4 < NODES / 4) v = cnt4[idx4];
    int s0 = v.x, s1 = s0 + v.y, s2 = s1 + v.z, s3 = s2 + v.w;
    int x = s3;
    for (int off = 1; off < 64; off <<= 1) {
      int y = __shfl_up(x, off, 64);
      if (lane >= off) x += y;
    }
    if (lane == 63) wsum[wid] = x;
    __syncthreads();
    if (wid == 0) {
      int w = (lane < 16) ? wsum[lane] : 0;
      for (int off = 1; off < 16; off <<= 1) {
        int y = __shfl_up(w, off, 64);
        if (lane >= off) w += y;
      }
      if (lane < 16) wsum[lane] = w;
    }
    __syncthreads();
    int waveoff = (wid == 0) ? 0 : wsum[wid - 1];
    int incl = s_carry + waveoff + x;
    int excl = incl - s3;
    if (idx4 < NODES / 4) {
      int o = idx4 * 4;
      row_start[o] = excl;          pos[o] = excl;
      row_start[o + 1] = excl + s0; pos[o + 1] = excl + s0;
      row_start[o + 2] = excl + s1; pos[o + 2] = excl + s1;
      row_start[o + 3] = excl + s2; pos[o + 3] = excl + s2;
    }
    __syncthreads();
    if (t == 1023) s_carry = incl;
    __syncthreads();
  }
  if (t == 0) row_start[NODES] = s_carry;
}

__global__ void scatter_kernel(const int* __restrict__ ei, int* __restrict__ pos,
                               int* __restrict__ csr_src) {
  int e = blockIdx.x * blockDim.x + threadIdx.x;
  if (e >= NTOT) return;
  int s, d;
  if (e < NEDGE) { s = ei[e]; d = ei[NEDGE + e]; } else { s = e - NEDGE; d = s; }
  int p = atomicAdd(&pos[d], 1);
  csr_src[p] = s;
}

// ---------------- all-layer attention coefs ----------------
// c_src[l,h,k] = sum_d W_l[k, h*128+d] * a_src[l,h,d]
__global__ void att_c_all_kernel(const float* __restrict__ gat_W,
                                 const float* __restrict__ a_src,
                                 const float* __restrict__ a_dst,
                                 float* __restrict__ c_src, float* __restrict__ c_dst) {
  int l = blockIdx.x >> 2;   // layer 0..2
  int h = blockIdx.x & 3;    // head 0..3
  int k = threadIdx.x;       // 0..127
  const float* wr = gat_W + l * HID * 512 + k * 512 + h * HID;
  const float* as = a_src + l * 512 + h * HID;
  const float* ad = a_dst + l * 512 + h * HID;
  float s1 = 0.f, s2 = 0.f;
  for (int d = 0; d < HID; d++) {
    float w = wr[d];
    s1 = fmaf(w, as[d], s1);
    s2 = fmaf(w, ad[d], s2);
  }
  c_src[l * 512 + h * HID + k] = s1;
  c_dst[l * 512 + h * HID + k] = s2;
}

// ---------------- node encoder + layer-0 e logits (fused) ----------------
// 4 nodes/block, one wave each; lane owns dims (2*lane, 2*lane+1).
__global__ __launch_bounds__(256) void node_enc_e_kernel(const float* __restrict__ x,
    const float* __restrict__ W, const float* __restrict__ b,
    const float* __restrict__ cs, const float* __restrict__ cd,
    float* __restrict__ h, float* __restrict__ e_s, float* __restrict__ e_d) {
  int lane = threadIdx.x & 63;
  int wid = threadIdx.x >> 6;
  int n = blockIdx.x * 4 + wid;
  const float* xr = x + n * 5;
  float x0 = xr[0], x1 = xr[1], x2 = xr[2], x3 = xr[3], x4 = xr[4];
  int d0 = lane * 2;
  float2 bb = *(const float2*)(b + d0);
  float h0 = bb.x, h1 = bb.y;
  {
    float2 w;
    w = *(const float2*)(W + 0 * HID + d0); h0 = fmaf(x0, w.x, h0); h1 = fmaf(x0, w.y, h1);
    w = *(const float2*)(W + 1 * HID + d0); h0 = fmaf(x1, w.x, h0); h1 = fmaf(x1, w.y, h1);
    w = *(const float2*)(W + 2 * HID + d0); h0 = fmaf(x2, w.x, h0); h1 = fmaf(x2, w.y, h1);
    w = *(const float2*)(W + 3 * HID + d0); h0 = fmaf(x3, w.x, h0); h1 = fmaf(x3, w.y, h1);
    w = *(const float2*)(W + 4 * HID + d0); h0 = fmaf(x4, w.x, h0); h1 = fmaf(x4, w.y, h1);
  }
  h0 = fmaxf(h0, 0.f); h1 = fmaxf(h1, 0.f);
  float2 hv = {h0, h1};
  ((float2*)(h + n * HID))[lane] = hv;
#pragma unroll
  for (int hh = 0; hh < HEADS; hh++) {
    float2 c1 = *(const float2*)(cs + hh * HID + d0);
    float2 c2 = *(const float2*)(cd + hh * HID + d0);
    float p = h0 * c1.x + h1 * c1.y;
    float q = h0 * c2.x + h1 * c2.y;
#pragma unroll
    for (int m = 32; m; m >>= 1) {
      p += __shfl_xor(p, m, 64);
      q += __shfl_xor(q, m, 64);
    }
    if (lane == 0) { e_s[n * HEADS + hh] = p; e_d[n * HEADS + hh] = q; }
  }
}

// ---------------- per-dst softmax + aggregation of raw h ----------------
// 4 nodes per block (one wave each). map!=null: node = map[idx], compact output row.
__global__ __launch_bounds__(256) void agg_kernel(const float* __restrict__ h,
    const float* __restrict__ e_src, const float* __restrict__ e_dst,
    const int* __restrict__ row_start, const int* __restrict__ csr_src,
    float* __restrict__ agg, const int* __restrict__ map) {
  __shared__ float4 wsh[4][128];
  __shared__ int ssh[4][128];
  int lane = threadIdx.x & 63;
  int wid = threadIdx.x >> 6;
  int idx = blockIdx.x * 4 + wid;
  int n = map ? map[idx] : idx;
  int r0 = row_start[n], r1 = row_start[n + 1];
  int deg = r1 - r0;
  const float4* es4 = (const float4*)e_src;
  float4 ed = ((const float4*)e_dst)[n];

  int s0 = -1, s1 = -1;
  float4 v0 = {-1e30f, -1e30f, -1e30f, -1e30f};
  float4 v1 = {-1e30f, -1e30f, -1e30f, -1e30f};
  {
    int e = r0 + lane;
    if (e < r1) {
      s0 = csr_src[e];
      float4 es = es4[s0];
      float a = es.x + ed.x, b = es.y + ed.y, c = es.z + ed.z, d = es.w + ed.w;
      v0.x = a > 0.f ? a : 0.2f * a; v0.y = b > 0.f ? b : 0.2f * b;
      v0.z = c > 0.f ? c : 0.2f * c; v0.w = d > 0.f ? d : 0.2f * d;
    }
    e = r0 + 64 + lane;
    if (e < r1) {
      s1 = csr_src[e];
      float4 es = es4[s1];
      float a = es.x + ed.x, b = es.y + ed.y, c = es.z + ed.z, d = es.w + ed.w;
      v1.x = a > 0.f ? a : 0.2f * a; v1.y = b > 0.f ? b : 0.2f * b;
      v1.z = c > 0.f ? c : 0.2f * c; v1.w = d > 0.f ? d : 0.2f * d;
    }
  }
  float4 mx;
  mx.x = fmaxf(v0.x, v1.x); mx.y = fmaxf(v0.y, v1.y);
  mx.z = fmaxf(v0.z, v1.z); mx.w = fmaxf(v0.w, v1.w);
  for (int e = r0 + 128 + lane; e < r1; e += 64) {
    int s = csr_src[e];
    float4 es = es4[s];
    float a = es.x + ed.x, b = es.y + ed.y, c = es.z + ed.z, d = es.w + ed.w;
    mx.x = fmaxf(mx.x, a > 0.f ? a : 0.2f * a);
    mx.y = fmaxf(mx.y, b > 0.f ? b : 0.2f * b);
    mx.z = fmaxf(mx.z, c > 0.f ? c : 0.2f * c);
    mx.w = fmaxf(mx.w, d > 0.f ? d : 0.2f * d);
  }
#pragma unroll
  for (int m = 32; m; m >>= 1) {
    mx.x = fmaxf(mx.x, __shfl_xor(mx.x, m, 64));
    mx.y = fmaxf(mx.y, __shfl_xor(mx.y, m, 64));
    mx.z = fmaxf(mx.z, __shfl_xor(mx.z, m, 64));
    mx.w = fmaxf(mx.w, __shfl_xor(mx.w, m, 64));
  }
  float4 p0 = {0.f, 0.f, 0.f, 0.f}, p1 = {0.f, 0.f, 0.f, 0.f};
  if (s0 >= 0) { p0.x = expf(v0.x - mx.x); p0.y = expf(v0.y - mx.y);
                 p0.z = expf(v0.z - mx.z); p0.w = expf(v0.w - mx.w); }
  if (s1 >= 0) { p1.x = expf(v1.x - mx.x); p1.y = expf(v1.y - mx.y);
                 p1.z = expf(v1.z - mx.z); p1.w = expf(v1.w - mx.w); }
  float4 sm;
  sm.x = p0.x + p1.x; sm.y = p0.y + p1.y; sm.z = p0.z + p1.z; sm.w = p0.w + p1.w;
  for (int e = r0 + 128 + lane; e < r1; e += 64) {
    int s = csr_src[e];
    float4 es = es4[s];
    float a = es.x + ed.x, b = es.y + ed.y, c = es.z + ed.z, d = es.w + ed.w;
    a = a > 0.f ? a : 0.2f * a; b = b > 0.f ? b : 0.2f * b;
    c = c > 0.f ? c : 0.2f * c; d = d > 0.f ? d : 0.2f * d;
    sm.x += expf(a - mx.x); sm.y += expf(b - mx.y);
    sm.z += expf(c - mx.z); sm.w += expf(d - mx.w);
  }
#pragma unroll
  for (int m = 32; m; m >>= 1) {
    sm.x += __shfl_xor(sm.x, m, 64);
    sm.y += __shfl_xor(sm.y, m, 64);
    sm.z += __shfl_xor(sm.z, m, 64);
    sm.w += __shfl_xor(sm.w, m, 64);
  }
  float4 inv;
  inv.x = 1.f / sm.x; inv.y = 1.f / sm.y; inv.z = 1.f / sm.z; inv.w = 1.f / sm.w;

  if (s0 >= 0) {
    float4 w; w.x = p0.x * inv.x; w.y = p0.y * inv.y; w.z = p0.z * inv.z; w.w = p0.w * inv.w;
    wsh[wid][lane] = w; ssh[wid][lane] = s0;
  }
  if (s1 >= 0) {
    float4 w; w.x = p1.x * inv.x; w.y = p1.y * inv.y; w.z = p1.z * inv.z; w.w = p1.w * inv.w;
    wsh[wid][64 + lane] = w; ssh[wid][64 + lane] = s1;
  }
  __builtin_amdgcn_s_waitcnt(0);  // drain lds writes (same-wave RAW)

  // accumulate dims (2*lane, 2*lane+1) per head; 2x unrolled, dual accumulators
  float2 a0 = {0.f, 0.f}, a1 = {0.f, 0.f}, a2 = {0.f, 0.f}, a3 = {0.f, 0.f};
  float2 b0 = {0.f, 0.f}, b1 = {0.f, 0.f}, b2 = {0.f, 0.f}, b3 = {0.f, 0.f};
  int mcap = deg < 128 ? deg : 128;
  int i = 0;
  for (; i + 2 <= mcap; i += 2) {
    float4 wA = wsh[wid][i];     int sA = ssh[wid][i];
    float4 wB = wsh[wid][i + 1]; int sB = ssh[wid][i + 1];
    float2 hA = ((const float2*)(h + sA * HID))[lane];
    float2 hB = ((const float2*)(h + sB * HID))[lane];
    a0.x = fmaf(wA.x, hA.x, a0.x); a0.y = fmaf(wA.x, hA.y, a0.y);
    a1.x = fmaf(wA.y, hA.x, a1.x); a1.y = fmaf(wA.y, hA.y, a1.y);
    a2.x = fmaf(wA.z, hA.x, a2.x); a2.y = fmaf(wA.z, hA.y, a2.y);
    a3.x = fmaf(wA.w, hA.x, a3.x); a3.y = fmaf(wA.w, hA.y, a3.y);
    b0.x = fmaf(wB.x, hB.x, b0.x); b0.y = fmaf(wB.x, hB.y, b0.y);
    b1.x = fmaf(wB.y, hB.x, b1.x); b1.y = fmaf(wB.y, hB.y, b1.y);
    b2.x = fmaf(wB.z, hB.x, b2.x); b2.y = fmaf(wB.z, hB.y, b2.y);
    b3.x = fmaf(wB.w, hB.x, b3.x); b3.y = fmaf(wB.w, hB.y, b3.y);
  }
  if (i < mcap) {
    float4 w = wsh[wid][i];
    int s = ssh[wid][i];
    float2 hv = ((const float2*)(h + s * HID))[lane];
    a0.x = fmaf(w.x, hv.x, a0.x); a0.y = fmaf(w.x, hv.y, a0.y);
    a1.x = fmaf(w.y, hv.x, a1.x); a1.y = fmaf(w.y, hv.y, a1.y);
    a2.x = fmaf(w.z, hv.x, a2.x); a2.y = fmaf(w.z, hv.y, a2.y);
    a3.x = fmaf(w.w, hv.x, a3.x); a3.y = fmaf(w.w, hv.y, a3.y);
  }
  a0.x += b0.x; a0.y += b0.y; a1.x += b1.x; a1.y += b1.y;
  a2.x += b2.x; a2.y += b2.y; a3.x += b3.x; a3.y += b3.y;
  for (int e = r0 + 128; e < r1; e++) {
    int s = csr_src[e];
    float4 es = es4[s];
    float a = es.x + ed.x, b = es.y + ed.y, c = es.z + ed.z, d = es.w + ed.w;
    a = a > 0.f ? a : 0.2f * a; b = b > 0.f ? b : 0.2f * b;
    c = c > 0.f ? c : 0.2f * c; d = d > 0.f ? d : 0.2f * d;
    float w0 = expf(a - mx.x) * inv.x, w1 = expf(b - mx.y) * inv.y;
    float w2 = expf(c - mx.z) * inv.z, w3 = expf(d - mx.w) * inv.w;
    float2 hv = ((const float2*)(h + s * HID))[lane];
    a0.x = fmaf(w0, hv.x, a0.x); a0.y = fmaf(w0, hv.y, a0.y);
    a1.x = fmaf(w1, hv.x, a1.x); a1.y = fmaf(w1, hv.y, a1.y);
    a2.x = fmaf(w2, hv.x, a2.x); a2.y = fmaf(w2, hv.y, a2.y);
    a3.x = fmaf(w3, hv.x, a3.x); a3.y = fmaf(w3, hv.y, a3.y);
  }
  float* ap = agg + idx * 512;
  ((float2*)(ap + 0 * 128))[lane] = a0;
  ((float2*)(ap + 1 * 128))[lane] = a1;
  ((float2*)(ap + 2 * 128))[lane] = a2;
  ((float2*)(ap + 3 * 128))[lane] = a3;
}

// ---------------- out = agg @ Wr /4 + b, LN, relu, residual (+ fused next-layer e) ----
// Tiled GEMM BM=32/BN=128/BK=32. map!=null: residual from h_in[map[row]], compact out.
// cs_next!=null: also compute e_s/e_d dots of the output row vs next layer's coefs.
__global__ __launch_bounds__(256) void out_ln_kernel(const float* __restrict__ agg,
    const float* __restrict__ W, const float* __restrict__ bias,
    const float* __restrict__ g, const float* __restrict__ b,
    const float* __restrict__ h_in, float* __restrict__ h_out,
    const int* __restrict__ map,
    const float* __restrict__ cs_next, const float* __restrict__ cd_next,
    float* __restrict__ e_s_out, float* __restrict__ e_d_out) {
  __shared__ float As[32][36];    // transposed A-tile [k][node], padded
  __shared__ float Bs[32][132];   // B-tile [k][dim], padded
  int tid = threadIdx.x;
  int nb = blockIdx.x * 32;
  int tdim = tid & 31;   // dims tdim*4 .. +3
  int tnode = tid >> 5;  // nodes tnode*4 .. +3
  float acc[4][4] = {};
  for (int kb = 0; kb < 512; kb += 32) {
    int hh = kb >> 7;
    int kk0 = kb & 127;
    __syncthreads();
    {
      int n = tid >> 3, kq = tid & 7;
      float4 v = *(const float4*)(agg + (nb + n) * 512 + kb + kq * 4);
      As[kq * 4 + 0][n] = v.x; As[kq * 4 + 1][n] = v.y;
      As[kq * 4 + 2][n] = v.z; As[kq * 4 + 3][n] = v.w;
#pragma unroll
      for (int i = 0; i < 4; i++) {
        int idx4 = tid + i * 256;
        int r = idx4 >> 5, dq = idx4 & 31;
        float4 w = *(const float4*)(W + (kk0 + r) * 512 + hh * 128 + dq * 4);
        *(float4*)&Bs[r][dq * 4] = w;
      }
    }
    __syncthreads();
#pragma unroll
    for (int k = 0; k < 32; k++) {
      float4 av = *(const float4*)&As[k][tnode * 4];
      float4 bv = *(const float4*)&Bs[k][tdim * 4];
      acc[0][0] = fmaf(av.x, bv.x, acc[0][0]); acc[0][1] = fmaf(av.x, bv.y, acc[0][1]);
      acc[0][2] = fmaf(av.x, bv.z, acc[0][2]); acc[0][3] = fmaf(av.x, bv.w, acc[0][3]);
      acc[1][0] = fmaf(av.y, bv.x, acc[1][0]); acc[1][1] = fmaf(av.y, bv.y, acc[1][1]);
      acc[1][2] = fmaf(av.y, bv.z, acc[1][2]); acc[1][3] = fmaf(av.y, bv.w, acc[1][3]);
      acc[2][0] = fmaf(av.z, bv.x, acc[2][0]); acc[2][1] = fmaf(av.z, bv.y, acc[2][1]);
      acc[2][2] = fmaf(av.z, bv.z, acc[2][2]); acc[2][3] = fmaf(av.z, bv.w, acc[2][3]);
      acc[3][0] = fmaf(av.w, bv.x, acc[3][0]); acc[3][1] = fmaf(av.w, bv.y, acc[3][1]);
      acc[3][2] = fmaf(av.w, bv.z, acc[3][2]); acc[3][3] = fmaf(av.w, bv.w, acc[3][3]);
    }
  }
  float4 bias4 = *(const float4*)(bias + tdim * 4);
  float4 g4 = *(const float4*)(g + tdim * 4);
  float4 b4 = *(const float4*)(b + tdim * 4);
  float4 cs4[4], cd4[4];
  if (cs_next) {
#pragma unroll
    for (int hh = 0; hh < 4; hh++) {
      cs4[hh] = *(const float4*)(cs_next + hh * 128 + tdim * 4);
      cd4[hh] = *(const float4*)(cd_next + hh * 128 + tdim * 4);
    }
  }
#pragma unroll
  for (int i = 0; i < 4; i++) {
    int row = nb + tnode * 4 + i;
    int res = map ? map[row] : row;
    float o0 = acc[i][0] * 0.25f + bias4.x;
    float o1 = acc[i][1] * 0.25f + bias4.y;
    float o2 = acc[i][2] * 0.25f + bias4.z;
    float o3 = acc[i][3] * 0.25f + bias4.w;
    float s1 = o0 + o1 + o2 + o3;
    float s2 = o0 * o0 + o1 * o1 + o2 * o2 + o3 * o3;
#pragma unroll
    for (int m = 1; m < 32; m <<= 1) {
      s1 += __shfl_xor(s1, m, 64);
      s2 += __shfl_xor(s2, m, 64);
    }
    float mu = s1 * 0.0078125f;
    float var = s2 * 0.0078125f - mu * mu;
    float r = 1.0f / sqrtf(var + 1e-5f);
    float4 hi = *(const float4*)(h_in + res * 128 + tdim * 4);
    float4 o;
    o.x = fmaxf((o0 - mu) * r * g4.x + b4.x, 0.f) + hi.x;
    o.y = fmaxf((o1 - mu) * r * g4.y + b4.y, 0.f) + hi.y;
    o.z = fmaxf((o2 - mu) * r * g4.z + b4.z, 0.f) + hi.z;
    o.w = fmaxf((o3 - mu) * r * g4.w + b4.w, 0.f) + hi.w;
    *(float4*)(h_out + row * 128 + tdim * 4) = o;
    if (cs_next) {
#pragma unroll
      for (int hh = 0; hh < 4; hh++) {
        float ps = o.x * cs4[hh].x + o.y * cs4[hh].y + o.z * cs4[hh].z + o.w * cs4[hh].w;
        float pd = o.x * cd4[hh].x + o.y * cd4[hh].y + o.z * cd4[hh].z + o.w * cd4[hh].w;
#pragma unroll
        for (int m = 1; m < 32; m <<= 1) {
          ps += __shfl_xor(ps, m, 64);
          pd += __shfl_xor(pd, m, 64);
        }
        if (tdim == 0) {
          e_s_out[row * 4 + hh] = ps;
          e_d_out[row * 4 + hh] = pd;
        }
      }
    }
  }
}

// ---------------- scorer: A = emb@sW1_top + b1, B = emb@sW1_bot ----------------
__global__ __launch_bounds__(128) void ab_kernel(const float* __restrict__ emb,
    const float* __restrict__ sW1, const float* __restrict__ sb1,
    float* __restrict__ As, float* __restrict__ Bs) {
  __shared__ float se[HID];
  int i = blockIdx.x;
  int k = threadIdx.x;
  se[k] = emb[i * HID + k];
  __syncthreads();
  float a = sb1[k], b = 0.f;
  for (int d = 0; d < HID; d++) {
    float e = se[d];
    a = fmaf(e, sW1[d * HID + k], a);
    b = fmaf(e, sW1[(HID + d) * HID + k], b);
  }
  As[i * HID + k] = a;
  Bs[i * HID + k] = b;
}

// ---------------- scorer main: 64 pairs (8i x 8j) x 128 n, 4x8 micro-tile ----------------
// (r7 config: bench-proven ~75us / VGPR 40 / occ 28%. LDS-pipe-bound at ~46% VALU.)
__global__ __launch_bounds__(256) void score_kernel(const float* __restrict__ As,
    const float* __restrict__ Bs, const float* __restrict__ sW2,
    const float* __restrict__ sb2, const float* __restrict__ sW3,
    const float* __restrict__ sb3, float* __restrict__ out) {
  int bx = blockIdx.x, by = blockIdx.y;
  if (bx > by) return;              // block fully below diagonal
  int i0 = bx * 8, j0 = by * 8;
  __shared__ float T1[32][68];      // [k][pair]
  __shared__ float W2s[32][132];    // [k][n]
  int tid = threadIdx.x;
  int tn = tid & 15;    // n-cols: tn*4..+3 and 64+tn*4..+3
  int tp = tid >> 4;    // pairs tp*4..+3 (tp 0..15)
  int sp = tid >> 2;
  int kq = (tid & 3) * 8;
  const float* arow = As + (i0 + (sp >> 3)) * 128;
  const float* brow = Bs + (j0 + (sp & 7)) * 128;
  float acc[4][8] = {};
  for (int kb = 0; kb < 128; kb += 32) {
    __syncthreads();
    {
      float4 a0 = *(const float4*)(arow + kb + kq);
      float4 b0 = *(const float4*)(brow + kb + kq);
      float4 a1 = *(const float4*)(arow + kb + kq + 4);
      float4 b1 = *(const float4*)(brow + kb + kq + 4);
      T1[kq + 0][sp] = fmaxf(a0.x + b0.x, 0.f);
      T1[kq + 1][sp] = fmaxf(a0.y + b0.y, 0.f);
      T1[kq + 2][sp] = fmaxf(a0.z + b0.z, 0.f);
      T1[kq + 3][sp] = fmaxf(a0.w + b0.w, 0.f);
      T1[kq + 4][sp] = fmaxf(a1.x + b1.x, 0.f);
      T1[kq + 5][sp] = fmaxf(a1.y + b1.y, 0.f);
      T1[kq + 6][sp] = fmaxf(a1.z + b1.z, 0.f);
      T1[kq + 7][sp] = fmaxf(a1.w + b1.w, 0.f);
#pragma unroll
      for (int i = 0; i < 4; i++) {
        int idx4 = tid + i * 256;
        int r = idx4 >> 5, c = (idx4 & 31) * 4;
        float4 w = *(const float4*)(sW2 + (kb + r) * 128 + c);
        *(float4*)&W2s[r][c] = w;
      }
    }
    __syncthreads();
#pragma unroll
    for (int k = 0; k < 32; k++) {
      float4 av  = *(const float4*)&T1[k][tp * 4];
      float4 bv0 = *(const float4*)&W2s[k][tn * 4];
      float4 bv1 = *(const float4*)&W2s[k][64 + tn * 4];
#pragma unroll
      for (int p = 0; p < 4; p++) {
        float a = (p == 0) ? av.x : (p == 1) ? av.y : (p == 2) ? av.z : av.w;
        acc[p][0] = fmaf(a, bv0.x, acc[p][0]); acc[p][1] = fmaf(a, bv0.y, acc[p][1]);
        acc[p][2] = fmaf(a, bv0.z, acc[p][2]); acc[p][3] = fmaf(a, bv0.w, acc[p][3]);
        acc[p][4] = fmaf(a, bv1.x, acc[p][4]); acc[p][5] = fmaf(a, bv1.y, acc[p][5]);
        acc[p][6] = fmaf(a, bv1.z, acc[p][6]); acc[p][7] = fmaf(a, bv1.w, acc[p][7]);
      }
    }
  }
  // epilogue: relu(t2+b2).w3, reduce over 16 tn-lanes
  float4 b2a = *(const float4*)(sb2 + tn * 4);
  float4 b2b = *(const float4*)(sb2 + 64 + tn * 4);
  float4 w3a = *(const float4*)(sW3 + tn * 4);
  float4 w3b = *(const float4*)(sW3 + 64 + tn * 4);
  float b3v = sb3[0];
#pragma unroll
  for (int pr = 0; pr < 4; pr++) {
    float s = fmaxf(acc[pr][0] + b2a.x, 0.f) * w3a.x
            + fmaxf(acc[pr][1] + b2a.y, 0.f) * w3a.y
            + fmaxf(acc[pr][2] + b2a.z, 0.f) * w3a.z
            + fmaxf(acc[pr][3] + b2a.w, 0.f) * w3a.w
            + fmaxf(acc[pr][4] + b2b.x, 0.f) * w3b.x
            + fmaxf(acc[pr][5] + b2b.y, 0.f) * w3b.y
            + fmaxf(acc[pr][6] + b2b.z, 0.f) * w3b.z
            + fmaxf(acc[pr][7] + b2b.w, 0.f) * w3b.w;
#pragma unroll
    for (int m = 1; m < 16; m <<= 1) s += __shfl_xor(s, m, 64);
    if (tn == 0) {
      int p = tp * 4 + pr;
      int i = i0 + (p >> 3), j = j0 + (p & 7);
      if (i < j) {
        float v = s + b3v;
        out[i * 512 + j] = v;
        out[j * 512 + i] = v;
      } else if (i == j) {
        out[i * 512 + j] = 0.f;
      }
    }
  }
}

// ---------------- launch ----------------
extern "C" void kernel_launch(void* const* d_in, const int* in_sizes, int n_in,
                              void* d_out, int out_size, void* d_ws, size_t ws_size,
                              hipStream_t stream) {
  const float* x       = (const float*)d_in[0];
  const int*   ei      = (const int*)d_in[1];
  const int*   odd     = (const int*)d_in[2];
  const float* node_W  = (const float*)d_in[3];
  const float* node_b  = (const float*)d_in[4];
  const float* gat_W   = (const float*)d_in[5];
  const float* att_src = (const float*)d_in[6];
  const float* att_dst = (const float*)d_in[7];
  const float* gat_b   = (const float*)d_in[8];
  const float* ln_g    = (const float*)d_in[9];
  const float* ln_b    = (const float*)d_in[10];
  const float* sW1     = (const float*)d_in[11];
  const float* sb1     = (const float*)d_in[12];
  const float* sW2     = (const float*)d_in[13];
  const float* sb2     = (const float*)d_in[14];
  const float* sW3     = (const float*)d_in[15];
  const float* sb3     = (const float*)d_in[16];
  float* out = (float*)d_out;

  float* f = (float*)d_ws;
  float* hA  = f; f += NODES * HID;
  float* hB  = f; f += NODES * HID;
  float* agg = f; f += NODES * 512;
  float* e_s = f; f += NODES * 4;
  float* e_d = f; f += NODES * 4;
  float* c_s = f; f += 3 * 512;
  float* c_d = f; f += 3 * 512;
  float* Asb = f; f += NODD * HID;
  float* Bsb = f; f += NODD * HID;
  float* emb = f; f += NODD * HID;
  int* cnt       = (int*)f;
  int* row_start = cnt + NODES;
  int* pos       = row_start + NODES + 1;
  int* csr       = pos + NODES;

  hipMemsetAsync(cnt, 0, NODES * sizeof(int), stream);
  hist_kernel<<<(NTOT + 255) / 256, 256, 0, stream>>>(ei, cnt);
  scan_kernel<<<1, 1024, 0, stream>>>(cnt, row_start, pos);
  scatter_kernel<<<(NTOT + 255) / 256, 256, 0, stream>>>(ei, pos, csr);
  att_c_all_kernel<<<12, 128, 0, stream>>>(gat_W, att_src, att_dst, c_s, c_d);
  // node encoder + layer-0 e logits
  node_enc_e_kernel<<<NODES / 4, 256, 0, stream>>>(x, node_W, node_b,
                                                   c_s, c_d, hA, e_s, e_d);

  const float* hc = hA;
  float* hn = hB;
  // layers 0,1: full-node; out_ln computes e for the NEXT layer
  for (int l = 0; l < 2; l++) {
    agg_kernel<<<NODES / 4, 256, 0, stream>>>(hc, e_s, e_d, row_start, csr, agg, nullptr);
    out_ln_kernel<<<NODES / 32, 256, 0, stream>>>(agg, gat_W + l * HID * 512,
                                                  gat_b + l * HID, ln_g + l * HID,
                                                  ln_b + l * HID, hc, hn, nullptr,
                                                  c_s + (l + 1) * 512, c_d + (l + 1) * 512,
                                                  e_s, e_d);
    float* t = (float*)hc; hc = hn; hn = t;
  }
  // layer 2: only odd vertices need output
  {
    const int l = 2;
    agg_kernel<<<NODD / 4, 256, 0, stream>>>(hc, e_s, e_d, row_start, csr, agg, odd);
    out_ln_kernel<<<NODD / 32, 256, 0, stream>>>(agg, gat_W + l * HID * 512,
                                                 gat_b + l * HID, ln_g + l * HID,
                                                 ln_b + l * HID, hc, emb, odd,
                                                 nullptr, nullptr, nullptr, nullptr);
  }
  ab_kernel<<<NODD, 128, 0, stream>>>(emb, sW1, sb1, Asb, Bsb);
  score_kernel<<<dim3(64, 64), 256, 0, stream>>>(Asb, Bsb, sW2, sb2, sW3, sb3, out);
}